// Round 9
// baseline (23.170 us; speedup 1.0000x reference)
//
#include <hip/hip_runtime.h>

// AtomDistances: out[b,i,j] = mask[b,i]&&mask[b,j]&&(i!=j)
//                  ? 1/(safe_norm(pos[b,nbr[b,i,j]] - pos[b,i]) + 1e-8) : 0
// B=4, A=2048.
//
// R9 = R8 with ONE change: plain stores instead of nontemporal. nt forced the
// 64MB output to stream to HBM every replay (WRITE_SIZE=66MB measured);
// without it the 128MB working set fits L3 and writes drain lazily.
// Everything else identical to R8 (2 rows/wave dual pipeline, depth-4
// prefetch, pre-barrier prefetch, rsqrt+fmin, x/yz packed LDS).

typedef float f4 __attribute__((ext_vector_type(4)));
typedef float f2 __attribute__((ext_vector_type(2)));

constexpr int A_DIM = 2048;
constexpr int WPB   = 8;            // waves per block
constexpr int RPB   = 16;           // rows per block (2 per wave)
constexpr int NTHR  = WPB * 64;     // 512

__global__ __launch_bounds__(NTHR, 8) void atom_distances_kernel(
    const float* __restrict__ pos,    // [B, A, 3]
    const int*   __restrict__ nbr,    // [B, A, A]
    const int*   __restrict__ mask,   // [B, A]
    float*       __restrict__ out) {  // [B, A, A]
  __shared__ float    sx[A_DIM];             // 8 KB
  __shared__ f2       syz[A_DIM];            // 16 KB
  __shared__ unsigned smaskbits[A_DIM / 32]; // 256 B

  const int blocks_per_b = A_DIM / RPB;      // 128
  const int b  = blockIdx.x / blocks_per_b;
  const int i0 = (blockIdx.x % blocks_per_b) * RPB;

  const float* posb  = pos  + (size_t)b * A_DIM * 3;
  const int*   maskb = mask + (size_t)b * A_DIM;

  const int w    = threadIdx.x >> 6;
  const int lane = threadIdx.x & 63;
  const int iA   = i0 + w;
  const int iB   = i0 + WPB + w;

  const int miA = maskb[iA];                 // wave-uniform broadcast loads
  const int miB = maskb[iB];
  const int* nrowA = nbr + ((size_t)b * A_DIM + iA) * A_DIM;
  const int* nrowB = nbr + ((size_t)b * A_DIM + iB) * A_DIM;

#define LDA(c) (*reinterpret_cast<const int4*>(nrowA + ((c) * 64 + lane) * 4))
#define LDB(c) (*reinterpret_cast<const int4*>(nrowB + ((c) * 64 + lane) * 4))

  // prefetch 2 chunks per active row BEFORE the barrier (hides under staging)
  int4 a0, a1, b0, b1;
  if (miA) { a0 = LDA(0); a1 = LDA(1); }
  if (miB) { b0 = LDB(0); b1 = LDB(1); }

  for (int t = threadIdx.x; t < A_DIM; t += NTHR) {
    sx[t] = posb[3 * t + 0];
    f2 yz; yz.x = posb[3 * t + 1]; yz.y = posb[3 * t + 2];
    syz[t] = yz;
  }
  for (int r = 0; r < A_DIM / NTHR; ++r) {   // 4 rounds
    const int t = r * NTHR + threadIdx.x;
    const unsigned long long bal = __ballot(maskb[t] != 0);
    if ((threadIdx.x & 63) == 0) {
      const int wbase = t >> 5;
      smaskbits[wbase]     = (unsigned)bal;
      smaskbits[wbase + 1] = (unsigned)(bal >> 32);
    }
  }
  __syncthreads();

  float* orowA = out + ((size_t)b * A_DIM + iA) * A_DIM;
  float* orowB = out + ((size_t)b * A_DIM + iB) * A_DIM;
  const f4 zf4 = {0.f, 0.f, 0.f, 0.f};

#define ZST(o_, c_) (*reinterpret_cast<f4*>((o_) + ((c_) * 64 + lane) * 4) = zf4)

  if (!miA && !miB) {  // both rows masked: stream zeros, exit
    #pragma unroll
    for (int c = 0; c < 8; ++c) { ZST(orowA, c); ZST(orowB, c); }
    return;
  }

#define ELEM(nt_, e_, dst_, i_, pix_, piyz_) { \
    const bool on_ = ((((wbits >> (bit + e_)) & 1u) != 0u) & ((i_) != j0 + e_)); \
    const int t_ = on_ ? ((nt_) & (A_DIM - 1)) : 0; \
    const float xx_ = sx[t_]; \
    const f2 yz_ = syz[t_]; \
    const float dx_ = xx_ - pix_; \
    const float dy_ = yz_.x - piyz_.x; \
    const float dz_ = yz_.y - piyz_.y; \
    const float d2_ = dx_ * dx_ + dy_ * dy_ + dz_ * dz_; \
    const float inv_ = fminf(__builtin_amdgcn_rsqf(d2_), 1e8f); \
    dst_ = on_ ? inv_ : 0.0f; }

#define CHUNKHDR(c) \
    const int j0 = ((c) * 64 + lane) * 4; \
    const unsigned wbits = smaskbits[(c) * 8 + (lane >> 3)]; \
    const int bit = (lane & 7) * 4;

#define PROC4(n_, i_, pix_, piyz_, orow_) { \
    f4 r_; \
    ELEM(n_.x, 0, r_.x, i_, pix_, piyz_); \
    ELEM(n_.y, 1, r_.y, i_, pix_, piyz_); \
    ELEM(n_.z, 2, r_.z, i_, pix_, piyz_); \
    ELEM(n_.w, 3, r_.w, i_, pix_, piyz_); \
    *reinterpret_cast<f4*>((orow_) + j0) = r_; }

  if (miA && miB) {  // dual interleaved pipelines, 4 int4 in flight
    const float pixA = sx[iA]; const f2 piyzA = syz[iA];
    const float pixB = sx[iB]; const f2 piyzB = syz[iB];
    { CHUNKHDR(0); PROC4(a0, iA, pixA, piyzA, orowA); PROC4(b0, iB, pixB, piyzB, orowB); }
    a0 = LDA(2); b0 = LDB(2);
    { CHUNKHDR(1); PROC4(a1, iA, pixA, piyzA, orowA); PROC4(b1, iB, pixB, piyzB, orowB); }
    a1 = LDA(3); b1 = LDB(3);
    { CHUNKHDR(2); PROC4(a0, iA, pixA, piyzA, orowA); PROC4(b0, iB, pixB, piyzB, orowB); }
    a0 = LDA(4); b0 = LDB(4);
    { CHUNKHDR(3); PROC4(a1, iA, pixA, piyzA, orowA); PROC4(b1, iB, pixB, piyzB, orowB); }
    a1 = LDA(5); b1 = LDB(5);
    { CHUNKHDR(4); PROC4(a0, iA, pixA, piyzA, orowA); PROC4(b0, iB, pixB, piyzB, orowB); }
    a0 = LDA(6); b0 = LDB(6);
    { CHUNKHDR(5); PROC4(a1, iA, pixA, piyzA, orowA); PROC4(b1, iB, pixB, piyzB, orowB); }
    a1 = LDA(7); b1 = LDB(7);
    { CHUNKHDR(6); PROC4(a0, iA, pixA, piyzA, orowA); PROC4(b0, iB, pixB, piyzB, orowB); }
    { CHUNKHDR(7); PROC4(a1, iA, pixA, piyzA, orowA); PROC4(b1, iB, pixB, piyzB, orowB); }
    return;
  }

  // exactly one active row: normalize (wave-uniform selects), R6 depth-4
  const int    i1    = miA ? iA : iB;
  const int*   nrow1 = miA ? nrowA : nrowB;
  float*       orow1 = miA ? orowA : orowB;
  float*       orow0 = miA ? orowB : orowA;  // inactive: zeros
  int4 n0 = miA ? a0 : b0;
  int4 n1 = miA ? a1 : b1;
  const float pix  = sx[i1];
  const f2    piyz = syz[i1];

#define LD1(c) (*reinterpret_cast<const int4*>(nrow1 + ((c) * 64 + lane) * 4))

  int4 n2 = LD1(2), n3 = LD1(3);
  { CHUNKHDR(0); PROC4(n0, i1, pix, piyz, orow1); ZST(orow0, 0); } n0 = LD1(4);
  { CHUNKHDR(1); PROC4(n1, i1, pix, piyz, orow1); ZST(orow0, 1); } n1 = LD1(5);
  { CHUNKHDR(2); PROC4(n2, i1, pix, piyz, orow1); ZST(orow0, 2); } n2 = LD1(6);
  { CHUNKHDR(3); PROC4(n3, i1, pix, piyz, orow1); ZST(orow0, 3); } n3 = LD1(7);
  { CHUNKHDR(4); PROC4(n0, i1, pix, piyz, orow1); ZST(orow0, 4); }
  { CHUNKHDR(5); PROC4(n1, i1, pix, piyz, orow1); ZST(orow0, 5); }
  { CHUNKHDR(6); PROC4(n2, i1, pix, piyz, orow1); ZST(orow0, 6); }
  { CHUNKHDR(7); PROC4(n3, i1, pix, piyz, orow1); ZST(orow0, 7); }

#undef LD1
#undef PROC4
#undef CHUNKHDR
#undef ELEM
#undef ZST
#undef LDA
#undef LDB
}

extern "C" void kernel_launch(void* const* d_in, const int* in_sizes, int n_in,
                              void* d_out, int out_size, void* d_ws, size_t ws_size,
                              hipStream_t stream) {
  const float* pos  = (const float*)d_in[0];  // [4,2048,3] f32
  const int*   nbr  = (const int*)d_in[1];    // [4,2048,2048] int32
  const int*   mask = (const int*)d_in[2];    // [4,2048] int32 (bool)
  float*       out  = (float*)d_out;          // [4,2048,2048] f32

  const int B = in_sizes[2] / A_DIM;          // 4
  const int grid = B * (A_DIM / RPB);         // 512 blocks

  atom_distances_kernel<<<grid, NTHR, 0, stream>>>(pos, nbr, mask, out);
}

// Round 10
// 23.161 us; speedup vs baseline: 1.0004x; 1.0004x over previous
//
#include <hip/hip_runtime.h>

// AtomDistances: out[b,i,j] = mask[b,i]&&mask[b,j]&&(i!=j)
//                  ? 1/(safe_norm(pos[b,nbr[b,i,j]] - pos[b,i]) + 1e-8) : 0
// B=4, A=2048.
//
// R10 = R8's per-row pipeline, restructured for dispatcher load-balancing:
// 256-thr blocks (4 waves, 1 row/wave) -> 2048 blocks, ~6 resident/CU
// (24.5 KB LDS) -> ~512 blocks backfill dynamically as masked-heavy blocks
// retire early. Atomic-free balancing (R5: same-line atomics serialize;
// R4: prepass node costs ~3us). nt stores kept (R9: plain stores +1.4us,
// WRITE_SIZE unchanged -> L3 doesn't absorb the output stream).

typedef float f4 __attribute__((ext_vector_type(4)));
typedef float f2 __attribute__((ext_vector_type(2)));

constexpr int A_DIM = 2048;
constexpr int WPB   = 4;            // waves per block = rows per block
constexpr int NTHR  = WPB * 64;     // 256

__global__ __launch_bounds__(NTHR, 6) void atom_distances_kernel(
    const float* __restrict__ pos,    // [B, A, 3]
    const int*   __restrict__ nbr,    // [B, A, A]
    const int*   __restrict__ mask,   // [B, A]
    float*       __restrict__ out) {  // [B, A, A]
  __shared__ float    sx[A_DIM];             // 8 KB
  __shared__ f2       syz[A_DIM];            // 16 KB
  __shared__ unsigned smaskbits[A_DIM / 32]; // 256 B

  const int blocks_per_b = A_DIM / WPB;      // 512
  const int b  = blockIdx.x / blocks_per_b;
  const int i0 = (blockIdx.x % blocks_per_b) * WPB;

  const float* posb  = pos  + (size_t)b * A_DIM * 3;
  const int*   maskb = mask + (size_t)b * A_DIM;

  const int w    = threadIdx.x >> 6;
  const int lane = threadIdx.x & 63;
  const int i    = i0 + w;

  const int  mi   = maskb[i];                // wave-uniform broadcast load
  const int* nrow = nbr + ((size_t)b * A_DIM + i) * A_DIM;

#define LDN(c) (*reinterpret_cast<const int4*>(nrow + ((c) * 64 + lane) * 4))

  // prefetch chunks 0,1 BEFORE the barrier (latency hides under staging)
  int4 n0, n1;
  if (mi) { n0 = LDN(0); n1 = LDN(1); }

  for (int t = threadIdx.x; t < A_DIM; t += NTHR) {   // 8 rounds
    sx[t] = posb[3 * t + 0];
    f2 yz; yz.x = posb[3 * t + 1]; yz.y = posb[3 * t + 2];
    syz[t] = yz;
  }
  for (int r = 0; r < A_DIM / NTHR; ++r) {            // 8 rounds
    const int t = r * NTHR + threadIdx.x;
    const unsigned long long bal = __ballot(maskb[t] != 0);
    if ((threadIdx.x & 63) == 0) {
      const int wbase = t >> 5;
      smaskbits[wbase]     = (unsigned)bal;
      smaskbits[wbase + 1] = (unsigned)(bal >> 32);
    }
  }
  __syncthreads();

  float* orow = out + ((size_t)b * A_DIM + i) * A_DIM;

  if (mi == 0) {  // masked row -> stream zeros, wave retires (frees slot)
    const f4 z = {0.f, 0.f, 0.f, 0.f};
    #pragma unroll
    for (int c = 0; c < 8; ++c)
      __builtin_nontemporal_store(z, reinterpret_cast<f4*>(orow + (c * 64 + lane) * 4));
    return;
  }

  const float pix  = sx[i];
  const f2    piyz = syz[i];

#define ELEM(nt_, e_, dst_) { \
    const bool on_ = ((((wbits >> (bit + e_)) & 1u) != 0u) & (i != j0 + e_)); \
    const int t_ = on_ ? ((nt_) & (A_DIM - 1)) : 0; \
    const float xx_ = sx[t_]; \
    const f2 yz_ = syz[t_]; \
    const float dx_ = xx_ - pix; \
    const float dy_ = yz_.x - piyz.x; \
    const float dz_ = yz_.y - piyz.y; \
    const float d2_ = dx_ * dx_ + dy_ * dy_ + dz_ * dz_; \
    const float inv_ = fminf(__builtin_amdgcn_rsqf(d2_), 1e8f); \
    dst_ = on_ ? inv_ : 0.0f; }

#define PROC(c, n) { \
    const int j0 = ((c) * 64 + lane) * 4; \
    const unsigned wbits = smaskbits[(c) * 8 + (lane >> 3)]; \
    const int bit = (lane & 7) * 4; \
    f4 r; \
    ELEM(n.x, 0, r.x); \
    ELEM(n.y, 1, r.y); \
    ELEM(n.z, 2, r.z); \
    ELEM(n.w, 3, r.w); \
    __builtin_nontemporal_store(r, reinterpret_cast<f4*>(orow + j0)); }

  // depth-4 rotating neighbor prefetch: 4 int4 always in flight
  int4 n2 = LDN(2), n3 = LDN(3);
  PROC(0, n0); n0 = LDN(4);
  PROC(1, n1); n1 = LDN(5);
  PROC(2, n2); n2 = LDN(6);
  PROC(3, n3); n3 = LDN(7);
  PROC(4, n0);
  PROC(5, n1);
  PROC(6, n2);
  PROC(7, n3);

#undef PROC
#undef ELEM
#undef LDN
}

extern "C" void kernel_launch(void* const* d_in, const int* in_sizes, int n_in,
                              void* d_out, int out_size, void* d_ws, size_t ws_size,
                              hipStream_t stream) {
  const float* pos  = (const float*)d_in[0];  // [4,2048,3] f32
  const int*   nbr  = (const int*)d_in[1];    // [4,2048,2048] int32
  const int*   mask = (const int*)d_in[2];    // [4,2048] int32 (bool)
  float*       out  = (float*)d_out;          // [4,2048,2048] f32

  const int B = in_sizes[2] / A_DIM;          // 4
  const int grid = B * (A_DIM / WPB);         // 2048 blocks

  atom_distances_kernel<<<grid, NTHR, 0, stream>>>(pos, nbr, mask, out);
}